// Round 8
// baseline (257.336 us; speedup 1.0000x reference)
//
#include <hip/hip_runtime.h>
#include <cstddef>
#include <math.h>

#define BD 8
#define TD 256
#define SD 256
#define HD 512
#define K2F 2.885390081777927f    // 2*log2(e): arg of exp2 for e^(2x)

#define EXP2(x) __builtin_amdgcn_exp2f(x)
#define RCP(x)  __builtin_amdgcn_rcpf(x)

typedef __attribute__((ext_vector_type(8))) _Float16 half8;
typedef __attribute__((ext_vector_type(4))) _Float16 half4;
typedef __attribute__((ext_vector_type(4))) float float4v;

// exp2 with arg clamped so E in [2^-80, 2^80]: products overflow to inf -> rcp -> 0,
// underflow to 0 -> r = 1; no inf*0 NaN path possible.
__device__ __forceinline__ float exp2_sat(float x) {
    return EXP2(fminf(fmaxf(x, -80.0f), 80.0f));
}

#define LSTR 40   // LDS row stride (halves) for proj staging

// ================= projK: proj (fp16 MFMA, fused convert), 1024 threads =================
// R4/R5/R7-verified body (absmax identical). One 64x64 tile per block;
// x=bid&7 (XCD/batch pin), k=bid>>3. Threads 0-511 stage A, 512-1023 stage B.
__global__ __launch_bounds__(1024) void projK(
    const float* __restrict__ enc, const float* __restrict__ qry,
    const float* __restrict__ Wh,  const float* __restrict__ Ws,
    float* __restrict__ encT, float* __restrict__ qryf)
{
    __shared__ float smem[2560];               // 10 KB: LA | LB

    const int bid = blockIdx.x;                // 0..511
    const int tid = threadIdx.x;               // 0..1023
    const int l  = tid & 63;
    const int w  = tid >> 6;                   // wave 0..15
    const int rf = l & 15;
    const int q  = l >> 4;

    _Float16* LA = (_Float16*)smem;            // 64*40 halves = 5120 B
    _Float16* LB = (_Float16*)(smem + 1280);   // +5120 B

    const int x  = bid & 7;                    // XCD / owning batch
    const int k  = bid >> 3;                   // 0..63
    const bool isq = k >= 32;
    const int kk = k & 31;                     // 0..31
    const int my = (isq ? 32 : 0) + x * 4 + (kk & 3);
    const int n0 = (kk >> 2) * 64;
    const int m0 = my * 64;                    // stacked row 0..4095

    const bool stagesA = (tid < 512);          // wave-uniform (waves 0-7 vs 8-15)
    const int srow = (tid >> 3) & 63;          // staging row 0..63
    const int scol = (tid & 7) * 4;            // staging col (floats)
    const float* Sbase = stagesA
        ? (isq ? qry + (size_t)(m0 - 2048 + srow) * HD
               : enc + (size_t)(m0 + srow) * HD) + scol
        : (isq ? Ws : Wh) + (size_t)(n0 + srow) * HD + scol;
    _Float16* Ldst = (stagesA ? LA : LB) + srow * LSTR + scol;

    const int mi = (w & 3) * 16;               // wave row-strip (4)
    const int ni = (w >> 2) * 16;              // wave col-strip (4)

    float4v acc = {0, 0, 0, 0};

    float4 a0 = *(const float4*)(Sbase);

    for (int ks = 0; ks < 16; ++ks) {
        if (ks) __syncthreads();
        {
            half4 ha;
            ha[0]=(_Float16)a0.x; ha[1]=(_Float16)a0.y; ha[2]=(_Float16)a0.z; ha[3]=(_Float16)a0.w;
            *(half4*)Ldst = ha;
        }
        __syncthreads();
        if (ks + 1 < 16) a0 = *(const float4*)(Sbase + (ks + 1) * 32);
        half8 ah = *(const half8*)&LA[(mi + rf) * LSTR + q * 8];
        half8 bh = *(const half8*)&LB[(ni + rf) * LSTR + q * 8];
        acc = __builtin_amdgcn_mfma_f32_16x16x32_f16(ah, bh, acc, 0, 0, 0);
    }

    // Epilogue (verified map: m-local = mi + q*4 + r, n-local = ni + rf).
    if (!isq) {
        const int b  = m0 >> 8;                // == x by construction
        const int sb = (m0 & 255) + mi + q * 4;
        float* base = encT + (size_t)b * HD * SD;
        float4 o = make_float4(exp2_sat(acc[0]*K2F), exp2_sat(acc[1]*K2F),
                               exp2_sat(acc[2]*K2F), exp2_sat(acc[3]*K2F));
        *(float4*)(base + (size_t)(n0 + ni + rf) * SD + sb) = o;
    } else {
        const int mrow = (m0 - 2048) + mi + q * 4;
        #pragma unroll
        for (int r = 0; r < 4; ++r)
            qryf[(size_t)(mrow + r) * HD + n0 + ni + rf] = exp2_sat(acc[r] * K2F);
    }
}

// ================= scoreK: score partials, j-halved for 2 blocks/CU =================
// Grid 512 = (b = bid&7 XCD pin) x (t-oct = (bid>>3)&31) x (j-half jh = bid>>8).
// Each block: 16 waves; wave w covers j in [jh*256 + w*16, +16). Same score body and
// 4-stage combine as the R7 attnK (proven); instead of softmax, writes the raw partial
// p[t][s] (sum over its j-half) to part[b][t][jh][s]. encT traffic unchanged vs attnK
// (each block reads only its 256 rows); 2 blocks/CU overlap the combine barrier-idle.
__global__ __launch_bounds__(1024, 8) void scoreK(
    const float* __restrict__ encT, const float* __restrict__ qryf,
    const float* __restrict__ v, float* __restrict__ part)
{
    __shared__ float smem[12288];    // 48 KB: qls[4096] | pls[8192]

    const int bid = blockIdx.x;      // 0..511
    const int tid = threadIdx.x;
    const int b    = bid & 7;
    const int toct = (bid >> 3) & 31;
    const int jh   = bid >> 8;       // 0 or 1
    const int t0   = toct * 8;
    const int l = tid & 63;
    const int w = tid >> 6;          // 0..15

    float* qls = smem;               // [t][j] 8*512 floats
    float* pls = smem + 4096;        // [4][8][256] floats

    {   // stage E_q: qls[t][j] (verbatim R7 staging; stages full j, half used)
        const float* qf = qryf + ((size_t)b * TD + t0) * HD;
        const int j = tid & 511;
        #pragma unroll
        for (int t = (tid >> 9); t < 8; t += 2)
            qls[t * 512 + j] = qf[t * HD + j];
    }
    __syncthreads();

    // ---- scores: wave w covers j in [jh*256 + w*16, +16); lane owns s = 4l..4l+3 ----
    float a[8][4];
    #pragma unroll
    for (int t = 0; t < 8; ++t)
        #pragma unroll
        for (int c = 0; c < 4; ++c) a[t][c] = 0.0f;
    {
        const int jbase = jh * 256 + w * 16;
        const float* ep = encT + (size_t)b * HD * SD + (size_t)jbase * SD + l * 4;
        #pragma unroll 4
        for (int jj = 0; jj < 16; ++jj) {
            float4 e = *(const float4*)(ep + (size_t)jj * SD);  // coalesced 1 KB/wave
            float vj = v[jbase + jj];                           // uniform -> s_load
            float qv[8];
            #pragma unroll
            for (int t = 0; t < 8; ++t) qv[t] = qls[t * 512 + jbase + jj];  // broadcast
            float ev[4] = {e.x, e.y, e.z, e.w};
            #pragma unroll
            for (int t = 0; t < 8; ++t)
                #pragma unroll
                for (int c = 0; c < 4; ++c) {
                    float p = fmaf(ev[c], qv[t], 1.0f);
                    a[t][c] = fmaf(vj, RCP(p), a[t][c]);
                }
        }
    }
    // ---- 4-slot partial combine, 4 stages (verbatim R7: slot g <- waves g,g+4,g+8,g+12) ----
    if (w < 4) {
        #pragma unroll
        for (int t = 0; t < 8; ++t)
            *(float4*)&pls[(w * 8 + t) * 256 + l * 4] =
                make_float4(a[t][0], a[t][1], a[t][2], a[t][3]);
    }
    __syncthreads();
    if (w >= 4 && w < 8) {
        #pragma unroll
        for (int t = 0; t < 8; ++t) {
            float4 c4 = *(const float4*)&pls[((w - 4) * 8 + t) * 256 + l * 4];
            c4.x += a[t][0]; c4.y += a[t][1]; c4.z += a[t][2]; c4.w += a[t][3];
            *(float4*)&pls[((w - 4) * 8 + t) * 256 + l * 4] = c4;
        }
    }
    __syncthreads();
    if (w >= 8 && w < 12) {
        #pragma unroll
        for (int t = 0; t < 8; ++t) {
            float4 c4 = *(const float4*)&pls[((w - 8) * 8 + t) * 256 + l * 4];
            c4.x += a[t][0]; c4.y += a[t][1]; c4.z += a[t][2]; c4.w += a[t][3];
            *(float4*)&pls[((w - 8) * 8 + t) * 256 + l * 4] = c4;
        }
    }
    __syncthreads();
    if (w >= 12) {
        #pragma unroll
        for (int t = 0; t < 8; ++t) {
            float4 c4 = *(const float4*)&pls[((w - 12) * 8 + t) * 256 + l * 4];
            c4.x += a[t][0]; c4.y += a[t][1]; c4.z += a[t][2]; c4.w += a[t][3];
            *(float4*)&pls[((w - 12) * 8 + t) * 256 + l * 4] = c4;
        }
    }
    __syncthreads();

    // ---- combine 4 slots, write partial: wave w<8 handles t=w; lane owns 4 s ----
    if (w < 8) {
        const int t = w;
        float p[4] = {0, 0, 0, 0};
        #pragma unroll
        for (int g = 0; g < 4; ++g) {
            float4 pp = *(const float4*)&pls[(g * 8 + t) * 256 + l * 4];
            p[0] += pp.x; p[1] += pp.y; p[2] += pp.z; p[3] += pp.w;
        }
        // part[b][t_global][jh][s], s contiguous (coalesced 1 KB/wave)
        *(float4*)&part[(((size_t)b * 256 + t0 + t) * 2 + jh) * 256 + l * 4] =
            make_float4(p[0], p[1], p[2], p[3]);
    }
}

// ================= attn2K: combine halves + masked softmax + AV (attn_fb tail) =========
// Grid 512 = (b = bid&7 XCD pin) x (t-quad tq = bid>>3). 512 threads.
__global__ __launch_bounds__(512) void attn2K(
    const float* __restrict__ enc, const float* __restrict__ part,
    const int* __restrict__ lens, float* __restrict__ out)
{
    __shared__ float avred[8192];    // [4 slots][4 t][512 h] 32 KB
    __shared__ float wls[4 * SD];    // 4 KB

    const int bid = blockIdx.x;      // 0..511
    const int tid = threadIdx.x;
    const int b   = bid & 7;
    const int t0  = (bid >> 3) * 4;
    const int w   = tid >> 6;
    const int l   = tid & 63;

    // ---- combine j-halves (deterministic order) + masked softmax: wave t<4 ----
    if (w < 4) {
        const int t = w;
        const int s0 = l * 4;
        const float* pb = part + (((size_t)b * 256 + t0 + t) * 2) * 256 + s0;
        float4 h0 = *(const float4*)(pb);
        float4 h1 = *(const float4*)(pb + 256);
        float p[4] = {h0.x + h1.x, h0.y + h1.y, h0.z + h1.z, h0.w + h1.w};
        const int len = lens[b];
        float sc[4];
        #pragma unroll
        for (int c = 0; c < 4; ++c)
            sc[c] = (s0 + c < len) ? -2.0f * p[c] : -INFINITY;
        float mx = fmaxf(fmaxf(sc[0], sc[1]), fmaxf(sc[2], sc[3]));
        #pragma unroll
        for (int off = 32; off; off >>= 1) mx = fmaxf(mx, __shfl_xor(mx, off));
        float ex[4]; float sum = 0.0f;
        #pragma unroll
        for (int c = 0; c < 4; ++c) { ex[c] = __expf(sc[c] - mx); sum += ex[c]; }
        #pragma unroll
        for (int off = 32; off; off >>= 1) sum += __shfl_xor(sum, off);
        const float inv = RCP(sum);
        *(float4*)&wls[t * SD + s0] = make_float4(ex[0]*inv, ex[1]*inv, ex[2]*inv, ex[3]*inv);
    }
    __syncthreads();

    // ---- AV: verbatim attn_fb tail (proven 7 rounds) ----
    const int g  = tid >> 7;          // 0..3
    const int h4 = (tid & 127) * 4;
    {
        const float* eb = enc + (size_t)b * SD * HD + h4;
        float4 o[4] = {{0,0,0,0},{0,0,0,0},{0,0,0,0},{0,0,0,0}};
        #pragma unroll 2
        for (int ss = 0; ss < 64; ++ss) {
            const int s = g * 64 + ss;
            float4 evv = *(const float4*)(eb + (size_t)s * HD);
            float wt[4];
            #pragma unroll
            for (int t = 0; t < 4; ++t) wt[t] = wls[t * SD + s];
            #pragma unroll
            for (int t = 0; t < 4; ++t) {
                o[t].x = fmaf(wt[t], evv.x, o[t].x);
                o[t].y = fmaf(wt[t], evv.y, o[t].y);
                o[t].z = fmaf(wt[t], evv.z, o[t].z);
                o[t].w = fmaf(wt[t], evv.w, o[t].w);
            }
        }
        #pragma unroll
        for (int t = 0; t < 4; ++t)
            *(float4*)&avred[(size_t)(g * 4 + t) * 512 + h4] = o[t];
    }
    __syncthreads();
    {
        const int t  = tid >> 7;
        const int hh = (tid & 127) * 4;
        float4 r = {0, 0, 0, 0};
        #pragma unroll
        for (int gg = 0; gg < 4; ++gg) {
            float4 x = *(const float4*)&avred[(size_t)(gg * 4 + t) * 512 + hh];
            r.x += x.x; r.y += x.y; r.z += x.z; r.w += x.w;
        }
        *(float4*)(out + ((size_t)b * TD + t0 + t) * HD + hh) = r;
    }
}

// ================= attnK: R7-proven fused attn (fallback if ws too small) =================
__global__ __launch_bounds__(1024) void attnK(
    const float* __restrict__ enc, const float* __restrict__ encT,
    const float* __restrict__ qryf, const float* __restrict__ v,
    const int* __restrict__ lens, float* __restrict__ out)
{
    __shared__ float smem[14336];    // 56 KB

    const int bid = blockIdx.x;      // 0..255
    const int tid = threadIdx.x;
    const int b   = bid & 7;
    const int t0  = (bid >> 3) * 8;
    const int l = tid & 63;
    const int w = tid >> 6;          // 0..15

    float* qls = smem;               // [t][j] 8*512 floats
    float* pls = smem + 4096;        // [4][8][256] floats; aliased avred
    float* wls = smem + 12288;       // [8][256] floats

    {
        const float* qf = qryf + ((size_t)b * TD + t0) * HD;
        const int j = tid & 511;
        #pragma unroll
        for (int t = (tid >> 9); t < 8; t += 2)
            qls[t * 512 + j] = qf[t * HD + j];
    }
    __syncthreads();

    float a[8][4];
    #pragma unroll
    for (int t = 0; t < 8; ++t)
        #pragma unroll
        for (int c = 0; c < 4; ++c) a[t][c] = 0.0f;
    {
        const int jbase = w * 32;
        const float* ep = encT + (size_t)b * HD * SD + (size_t)jbase * SD + l * 4;
        #pragma unroll 4
        for (int jj = 0; jj < 32; ++jj) {
            float4 e = *(const float4*)(ep + (size_t)jj * SD);
            float vj = v[jbase + jj];
            float qv[8];
            #pragma unroll
            for (int t = 0; t < 8; ++t) qv[t] = qls[t * 512 + jbase + jj];
            float ev[4] = {e.x, e.y, e.z, e.w};
            #pragma unroll
            for (int t = 0; t < 8; ++t)
                #pragma unroll
                for (int c = 0; c < 4; ++c) {
                    float p = fmaf(ev[c], qv[t], 1.0f);
                    a[t][c] = fmaf(vj, RCP(p), a[t][c]);
                }
        }
    }
    if (w < 4) {
        #pragma unroll
        for (int t = 0; t < 8; ++t)
            *(float4*)&pls[(w * 8 + t) * 256 + l * 4] =
                make_float4(a[t][0], a[t][1], a[t][2], a[t][3]);
    }
    __syncthreads();
    if (w >= 4 && w < 8) {
        #pragma unroll
        for (int t = 0; t < 8; ++t) {
            float4 c4 = *(const float4*)&pls[((w - 4) * 8 + t) * 256 + l * 4];
            c4.x += a[t][0]; c4.y += a[t][1]; c4.z += a[t][2]; c4.w += a[t][3];
            *(float4*)&pls[((w - 4) * 8 + t) * 256 + l * 4] = c4;
        }
    }
    __syncthreads();
    if (w >= 8 && w < 12) {
        #pragma unroll
        for (int t = 0; t < 8; ++t) {
            float4 c4 = *(const float4*)&pls[((w - 8) * 8 + t) * 256 + l * 4];
            c4.x += a[t][0]; c4.y += a[t][1]; c4.z += a[t][2]; c4.w += a[t][3];
            *(float4*)&pls[((w - 8) * 8 + t) * 256 + l * 4] = c4;
        }
    }
    __syncthreads();
    if (w >= 12) {
        #pragma unroll
        for (int t = 0; t < 8; ++t) {
            float4 c4 = *(const float4*)&pls[((w - 12) * 8 + t) * 256 + l * 4];
            c4.x += a[t][0]; c4.y += a[t][1]; c4.z += a[t][2]; c4.w += a[t][3];
            *(float4*)&pls[((w - 12) * 8 + t) * 256 + l * 4] = c4;
        }
    }
    __syncthreads();

    if (w < 8) {
        const int t = w;
        float p[4] = {0, 0, 0, 0};
        #pragma unroll
        for (int g = 0; g < 4; ++g) {
            float4 pp = *(const float4*)&pls[(g * 8 + t) * 256 + l * 4];
            p[0] += pp.x; p[1] += pp.y; p[2] += pp.z; p[3] += pp.w;
        }
        const int len = lens[b];
        const int s0 = l * 4;
        float sc[4];
        #pragma unroll
        for (int c = 0; c < 4; ++c)
            sc[c] = (s0 + c < len) ? -2.0f * p[c] : -INFINITY;
        float mx = fmaxf(fmaxf(sc[0], sc[1]), fmaxf(sc[2], sc[3]));
        #pragma unroll
        for (int off = 32; off; off >>= 1) mx = fmaxf(mx, __shfl_xor(mx, off));
        float ex[4]; float sum = 0.0f;
        #pragma unroll
        for (int c = 0; c < 4; ++c) { ex[c] = __expf(sc[c] - mx); sum += ex[c]; }
        #pragma unroll
        for (int off = 32; off; off >>= 1) sum += __shfl_xor(sum, off);
        const float inv = RCP(sum);
        *(float4*)&wls[t * SD + s0] = make_float4(ex[0]*inv, ex[1]*inv, ex[2]*inv, ex[3]*inv);
    }
    __syncthreads();

    const int sg = tid >> 7;
    const int h4 = (tid & 127) * 4;
    float* avred = pls;
    float4 o[8];
    #pragma unroll
    for (int t = 0; t < 8; ++t) o[t] = make_float4(0.f, 0.f, 0.f, 0.f);
    {
        const float* eb = enc + (size_t)b * SD * HD + h4;
        #pragma unroll 2
        for (int ss = 0; ss < 32; ++ss) {
            const int s = sg * 32 + ss;
            float4 evv = *(const float4*)(eb + (size_t)s * HD);
            float wt[8];
            #pragma unroll
            for (int t = 0; t < 8; ++t) wt[t] = wls[t * SD + s];
            #pragma unroll
            for (int t = 0; t < 8; ++t) {
                o[t].x = fmaf(wt[t], evv.x, o[t].x);
                o[t].y = fmaf(wt[t], evv.y, o[t].y);
                o[t].z = fmaf(wt[t], evv.z, o[t].z);
                o[t].w = fmaf(wt[t], evv.w, o[t].w);
            }
        }
    }
    if (sg < 2) {
        #pragma unroll
        for (int t = 0; t < 8; ++t)
            *(float4*)&avred[(size_t)(sg * 8 + t) * 512 + h4] = o[t];
    }
    __syncthreads();
    if (sg >= 2 && sg < 4) {
        #pragma unroll
        for (int t = 0; t < 8; ++t) {
            float4 c4 = *(const float4*)&avred[(size_t)((sg - 2) * 8 + t) * 512 + h4];
            c4.x += o[t].x; c4.y += o[t].y; c4.z += o[t].z; c4.w += o[t].w;
            *(float4*)&avred[(size_t)((sg - 2) * 8 + t) * 512 + h4] = c4;
        }
    }
    __syncthreads();
    if (sg >= 4 && sg < 6) {
        #pragma unroll
        for (int t = 0; t < 8; ++t) {
            float4 c4 = *(const float4*)&avred[(size_t)((sg - 4) * 8 + t) * 512 + h4];
            c4.x += o[t].x; c4.y += o[t].y; c4.z += o[t].z; c4.w += o[t].w;
            *(float4*)&avred[(size_t)((sg - 4) * 8 + t) * 512 + h4] = c4;
        }
    }
    __syncthreads();
    if (sg >= 6) {
        #pragma unroll
        for (int t = 0; t < 8; ++t) {
            float4 c4 = *(const float4*)&avred[(size_t)((sg - 6) * 8 + t) * 512 + h4];
            c4.x += o[t].x; c4.y += o[t].y; c4.z += o[t].z; c4.w += o[t].w;
            *(float4*)&avred[(size_t)((sg - 6) * 8 + t) * 512 + h4] = c4;
        }
    }
    __syncthreads();

    {
        const int t  = tid >> 7;
        const int hh = (tid & 127) * 4;
        float4 x0 = *(const float4*)&avred[(size_t)(0 * 8 + t) * 512 + hh];
        float4 x1 = *(const float4*)&avred[(size_t)(1 * 8 + t) * 512 + hh];
        float4 r = make_float4(x0.x + x1.x, x0.y + x1.y, x0.z + x1.z, x0.w + x1.w);
        *(float4*)(out + ((size_t)b * TD + t0 + t) * HD + hh) = r;
    }
}

extern "C" void kernel_launch(void* const* d_in, const int* in_sizes, int n_in,
                              void* d_out, int out_size, void* d_ws, size_t ws_size,
                              hipStream_t stream) {
    const float* query = (const float*)d_in[0];
    const float* enc   = (const float*)d_in[1];
    const int*   lens  = (const int*)d_in[2];
    const float* W_h   = (const float*)d_in[3];
    const float* W_s   = (const float*)d_in[4];
    const float* v     = (const float*)d_in[5];
    float* out = (float*)d_out;

    char* ws = (char*)d_ws;
    float* encT = (float*)(ws);                       // 4 MB (B,H,S)  E_e
    float* qryf = (float*)(ws + ((size_t)4 << 20));   // 4 MB (B,T,H)  E_q
    float* part = (float*)(ws + ((size_t)8 << 20));   // 4 MB (B,T,2,S) score partials

    // Plain launches only — graph-capture-safe (R7 lesson: cooperative launch fails
    // under capture and silently forced the fallback for 7 rounds).
    projK<<<dim3(512), dim3(1024), 0, stream>>>(enc, query, W_h, W_s, encT, qryf);

    if (ws_size >= ((size_t)12 << 20)) {
        // j-halved score (2 blocks/CU) + proven softmax/AV tail.
        scoreK<<<dim3(512), dim3(1024), 0, stream>>>(encT, qryf, v, part);
        attn2K<<<dim3(512), dim3(512),  0, stream>>>(enc, part, lens, out);
    } else {
        // R7-proven fused attn.
        attnK<<<dim3(256), dim3(1024), 0, stream>>>(enc, encT, qryf, v, lens, out);
    }
}

// Round 9
// 117.848 us; speedup vs baseline: 2.1836x; 2.1836x over previous
//
#include <hip/hip_runtime.h>
#include <cstddef>
#include <math.h>

#define BD 8
#define TD 256
#define SD 256
#define HD 512
#define K2F 2.885390081777927f    // 2*log2(e): arg of exp2 for e^(2x)

#define EXP2(x) __builtin_amdgcn_exp2f(x)
#define RCP(x)  __builtin_amdgcn_rcpf(x)

typedef __attribute__((ext_vector_type(8))) _Float16 half8;
typedef __attribute__((ext_vector_type(4))) _Float16 half4;
typedef __attribute__((ext_vector_type(4))) float float4v;

// exp2 with arg clamped so E in [2^-80, 2^80]: products overflow to inf -> rcp -> 0,
// underflow to 0 -> r = 1; no inf*0 NaN path possible.
__device__ __forceinline__ float exp2_sat(float x) {
    return EXP2(fminf(fmaxf(x, -80.0f), 80.0f));
}

#define LSTR 40   // LDS row stride (halves) for proj staging

// ================= projK: proj (fp16 MFMA, fused convert), 1024 threads =================
// R4/R5/R7-verified body (absmax identical). One 64x64 tile per block;
// x=bid&7 (XCD/batch pin), k=bid>>3. Threads 0-511 stage A, 512-1023 stage B.
__global__ __launch_bounds__(1024) void projK(
    const float* __restrict__ enc, const float* __restrict__ qry,
    const float* __restrict__ Wh,  const float* __restrict__ Ws,
    float* __restrict__ encT, float* __restrict__ qryf)
{
    __shared__ float smem[2560];               // 10 KB: LA | LB

    const int bid = blockIdx.x;                // 0..511
    const int tid = threadIdx.x;               // 0..1023
    const int l  = tid & 63;
    const int w  = tid >> 6;                   // wave 0..15
    const int rf = l & 15;
    const int q  = l >> 4;

    _Float16* LA = (_Float16*)smem;            // 64*40 halves = 5120 B
    _Float16* LB = (_Float16*)(smem + 1280);   // +5120 B

    const int x  = bid & 7;                    // XCD / owning batch
    const int k  = bid >> 3;                   // 0..63
    const bool isq = k >= 32;
    const int kk = k & 31;                     // 0..31
    const int my = (isq ? 32 : 0) + x * 4 + (kk & 3);
    const int n0 = (kk >> 2) * 64;
    const int m0 = my * 64;                    // stacked row 0..4095

    const bool stagesA = (tid < 512);          // wave-uniform (waves 0-7 vs 8-15)
    const int srow = (tid >> 3) & 63;          // staging row 0..63
    const int scol = (tid & 7) * 4;            // staging col (floats)
    const float* Sbase = stagesA
        ? (isq ? qry + (size_t)(m0 - 2048 + srow) * HD
               : enc + (size_t)(m0 + srow) * HD) + scol
        : (isq ? Ws : Wh) + (size_t)(n0 + srow) * HD + scol;
    _Float16* Ldst = (stagesA ? LA : LB) + srow * LSTR + scol;

    const int mi = (w & 3) * 16;               // wave row-strip (4)
    const int ni = (w >> 2) * 16;              // wave col-strip (4)

    float4v acc = {0, 0, 0, 0};

    float4 a0 = *(const float4*)(Sbase);

    for (int ks = 0; ks < 16; ++ks) {
        if (ks) __syncthreads();
        {
            half4 ha;
            ha[0]=(_Float16)a0.x; ha[1]=(_Float16)a0.y; ha[2]=(_Float16)a0.z; ha[3]=(_Float16)a0.w;
            *(half4*)Ldst = ha;
        }
        __syncthreads();
        if (ks + 1 < 16) a0 = *(const float4*)(Sbase + (ks + 1) * 32);
        half8 ah = *(const half8*)&LA[(mi + rf) * LSTR + q * 8];
        half8 bh = *(const half8*)&LB[(ni + rf) * LSTR + q * 8];
        acc = __builtin_amdgcn_mfma_f32_16x16x32_f16(ah, bh, acc, 0, 0, 0);
    }

    // Epilogue (verified map: m-local = mi + q*4 + r, n-local = ni + rf).
    if (!isq) {
        const int b  = m0 >> 8;                // == x by construction
        const int sb = (m0 & 255) + mi + q * 4;
        float* base = encT + (size_t)b * HD * SD;
        float4 o = make_float4(exp2_sat(acc[0]*K2F), exp2_sat(acc[1]*K2F),
                               exp2_sat(acc[2]*K2F), exp2_sat(acc[3]*K2F));
        *(float4*)(base + (size_t)(n0 + ni + rf) * SD + sb) = o;
    } else {
        const int mrow = (m0 - 2048) + mi + q * 4;
        #pragma unroll
        for (int r = 0; r < 4; ++r)
            qryf[(size_t)(mrow + r) * HD + n0 + ni + rf] = exp2_sat(acc[r] * K2F);
    }
}

// ================= scoreK: score partials, j-halved for 2 blocks/CU =================
// R8 lesson: __launch_bounds__(1024, 8) clamped VGPR to 32 -> a[8][4] spilled to
// scratch (WRITE_SIZE 500 MB, 174 us). Plain __launch_bounds__(1024) lets the
// allocator land ~52 VGPR (like R7 attnK, same body) -> <=64 VGPR gives 2 blocks/CU
// naturally. Numerics of this kernel + attn2K are R8-verified (absmax identical).
// Grid 512 = (b = bid&7 XCD pin) x (t-oct) x (j-half jh = bid>>8).
__global__ __launch_bounds__(1024) void scoreK(
    const float* __restrict__ encT, const float* __restrict__ qryf,
    const float* __restrict__ v, float* __restrict__ part)
{
    __shared__ float smem[12288];    // 48 KB: qls[4096] | pls[8192]

    const int bid = blockIdx.x;      // 0..511
    const int tid = threadIdx.x;
    const int b    = bid & 7;
    const int toct = (bid >> 3) & 31;
    const int jh   = bid >> 8;       // 0 or 1
    const int t0   = toct * 8;
    const int l = tid & 63;
    const int w = tid >> 6;          // 0..15

    float* qls = smem;               // [t][j] 8*512 floats
    float* pls = smem + 4096;        // [4][8][256] floats

    {   // stage E_q: qls[t][j]
        const float* qf = qryf + ((size_t)b * TD + t0) * HD;
        const int j = tid & 511;
        #pragma unroll
        for (int t = (tid >> 9); t < 8; t += 2)
            qls[t * 512 + j] = qf[t * HD + j];
    }
    __syncthreads();

    // ---- scores: wave w covers j in [jh*256 + w*16, +16); lane owns s = 4l..4l+3 ----
    float a[8][4];
    #pragma unroll
    for (int t = 0; t < 8; ++t)
        #pragma unroll
        for (int c = 0; c < 4; ++c) a[t][c] = 0.0f;
    {
        const int jbase = jh * 256 + w * 16;
        const float* ep = encT + (size_t)b * HD * SD + (size_t)jbase * SD + l * 4;
        #pragma unroll 4
        for (int jj = 0; jj < 16; ++jj) {
            float4 e = *(const float4*)(ep + (size_t)jj * SD);  // coalesced 1 KB/wave
            float vj = v[jbase + jj];                           // uniform -> s_load
            float qv[8];
            #pragma unroll
            for (int t = 0; t < 8; ++t) qv[t] = qls[t * 512 + jbase + jj];  // broadcast
            float ev[4] = {e.x, e.y, e.z, e.w};
            #pragma unroll
            for (int t = 0; t < 8; ++t)
                #pragma unroll
                for (int c = 0; c < 4; ++c) {
                    float p = fmaf(ev[c], qv[t], 1.0f);
                    a[t][c] = fmaf(vj, RCP(p), a[t][c]);
                }
        }
    }
    // ---- 4-slot partial combine, 4 stages (slot g <- waves g, g+4, g+8, g+12) ----
    if (w < 4) {
        #pragma unroll
        for (int t = 0; t < 8; ++t)
            *(float4*)&pls[(w * 8 + t) * 256 + l * 4] =
                make_float4(a[t][0], a[t][1], a[t][2], a[t][3]);
    }
    __syncthreads();
    if (w >= 4 && w < 8) {
        #pragma unroll
        for (int t = 0; t < 8; ++t) {
            float4 c4 = *(const float4*)&pls[((w - 4) * 8 + t) * 256 + l * 4];
            c4.x += a[t][0]; c4.y += a[t][1]; c4.z += a[t][2]; c4.w += a[t][3];
            *(float4*)&pls[((w - 4) * 8 + t) * 256 + l * 4] = c4;
        }
    }
    __syncthreads();
    if (w >= 8 && w < 12) {
        #pragma unroll
        for (int t = 0; t < 8; ++t) {
            float4 c4 = *(const float4*)&pls[((w - 8) * 8 + t) * 256 + l * 4];
            c4.x += a[t][0]; c4.y += a[t][1]; c4.z += a[t][2]; c4.w += a[t][3];
            *(float4*)&pls[((w - 8) * 8 + t) * 256 + l * 4] = c4;
        }
    }
    __syncthreads();
    if (w >= 12) {
        #pragma unroll
        for (int t = 0; t < 8; ++t) {
            float4 c4 = *(const float4*)&pls[((w - 12) * 8 + t) * 256 + l * 4];
            c4.x += a[t][0]; c4.y += a[t][1]; c4.z += a[t][2]; c4.w += a[t][3];
            *(float4*)&pls[((w - 12) * 8 + t) * 256 + l * 4] = c4;
        }
    }
    __syncthreads();

    // ---- combine 4 slots, write partial: wave w<8 handles t=w; lane owns 4 s ----
    if (w < 8) {
        const int t = w;
        float p[4] = {0, 0, 0, 0};
        #pragma unroll
        for (int g = 0; g < 4; ++g) {
            float4 pp = *(const float4*)&pls[(g * 8 + t) * 256 + l * 4];
            p[0] += pp.x; p[1] += pp.y; p[2] += pp.z; p[3] += pp.w;
        }
        // part[b][t_global][jh][s], s contiguous (coalesced 1 KB/wave)
        *(float4*)&part[(((size_t)b * 256 + t0 + t) * 2 + jh) * 256 + l * 4] =
            make_float4(p[0], p[1], p[2], p[3]);
    }
}

// ================= attn2K: combine halves + masked softmax + AV (attn_fb tail) =========
// R8-verified numerics. Grid 512 = (b = bid&7 XCD pin) x (t-quad). 512 threads.
__global__ __launch_bounds__(512) void attn2K(
    const float* __restrict__ enc, const float* __restrict__ part,
    const int* __restrict__ lens, float* __restrict__ out)
{
    __shared__ float avred[8192];    // [4 slots][4 t][512 h] 32 KB
    __shared__ float wls[4 * SD];    // 4 KB

    const int bid = blockIdx.x;      // 0..511
    const int tid = threadIdx.x;
    const int b   = bid & 7;
    const int t0  = (bid >> 3) * 4;
    const int w   = tid >> 6;
    const int l   = tid & 63;

    // ---- combine j-halves (deterministic order) + masked softmax: wave t<4 ----
    if (w < 4) {
        const int t = w;
        const int s0 = l * 4;
        const float* pb = part + (((size_t)b * 256 + t0 + t) * 2) * 256 + s0;
        float4 h0 = *(const float4*)(pb);
        float4 h1 = *(const float4*)(pb + 256);
        float p[4] = {h0.x + h1.x, h0.y + h1.y, h0.z + h1.z, h0.w + h1.w};
        const int len = lens[b];
        float sc[4];
        #pragma unroll
        for (int c = 0; c < 4; ++c)
            sc[c] = (s0 + c < len) ? -2.0f * p[c] : -INFINITY;
        float mx = fmaxf(fmaxf(sc[0], sc[1]), fmaxf(sc[2], sc[3]));
        #pragma unroll
        for (int off = 32; off; off >>= 1) mx = fmaxf(mx, __shfl_xor(mx, off));
        float ex[4]; float sum = 0.0f;
        #pragma unroll
        for (int c = 0; c < 4; ++c) { ex[c] = __expf(sc[c] - mx); sum += ex[c]; }
        #pragma unroll
        for (int off = 32; off; off >>= 1) sum += __shfl_xor(sum, off);
        const float inv = RCP(sum);
        *(float4*)&wls[t * SD + s0] = make_float4(ex[0]*inv, ex[1]*inv, ex[2]*inv, ex[3]*inv);
    }
    __syncthreads();

    // ---- AV: verbatim attn_fb tail (proven 8 rounds) ----
    const int g  = tid >> 7;          // 0..3
    const int h4 = (tid & 127) * 4;
    {
        const float* eb = enc + (size_t)b * SD * HD + h4;
        float4 o[4] = {{0,0,0,0},{0,0,0,0},{0,0,0,0},{0,0,0,0}};
        #pragma unroll 2
        for (int ss = 0; ss < 64; ++ss) {
            const int s = g * 64 + ss;
            float4 evv = *(const float4*)(eb + (size_t)s * HD);
            float wt[4];
            #pragma unroll
            for (int t = 0; t < 4; ++t) wt[t] = wls[t * SD + s];
            #pragma unroll
            for (int t = 0; t < 4; ++t) {
                o[t].x = fmaf(wt[t], evv.x, o[t].x);
                o[t].y = fmaf(wt[t], evv.y, o[t].y);
                o[t].z = fmaf(wt[t], evv.z, o[t].z);
                o[t].w = fmaf(wt[t], evv.w, o[t].w);
            }
        }
        #pragma unroll
        for (int t = 0; t < 4; ++t)
            *(float4*)&avred[(size_t)(g * 4 + t) * 512 + h4] = o[t];
    }
    __syncthreads();
    {
        const int t  = tid >> 7;
        const int hh = (tid & 127) * 4;
        float4 r = {0, 0, 0, 0};
        #pragma unroll
        for (int gg = 0; gg < 4; ++gg) {
            float4 x = *(const float4*)&avred[(size_t)(gg * 4 + t) * 512 + hh];
            r.x += x.x; r.y += x.y; r.z += x.z; r.w += x.w;
        }
        *(float4*)(out + ((size_t)b * TD + t0 + t) * HD + hh) = r;
    }
}

// ================= attnK: R7-proven fused attn (fallback; bench 119, 45.7 us) =============
__global__ __launch_bounds__(1024) void attnK(
    const float* __restrict__ enc, const float* __restrict__ encT,
    const float* __restrict__ qryf, const float* __restrict__ v,
    const int* __restrict__ lens, float* __restrict__ out)
{
    __shared__ float smem[14336];    // 56 KB

    const int bid = blockIdx.x;      // 0..255
    const int tid = threadIdx.x;
    const int b   = bid & 7;
    const int t0  = (bid >> 3) * 8;
    const int l = tid & 63;
    const int w = tid >> 6;          // 0..15

    float* qls = smem;               // [t][j] 8*512 floats
    float* pls = smem + 4096;        // [4][8][256] floats; aliased avred
    float* wls = smem + 12288;       // [8][256] floats

    {
        const float* qf = qryf + ((size_t)b * TD + t0) * HD;
        const int j = tid & 511;
        #pragma unroll
        for (int t = (tid >> 9); t < 8; t += 2)
            qls[t * 512 + j] = qf[t * HD + j];
    }
    __syncthreads();

    float a[8][4];
    #pragma unroll
    for (int t = 0; t < 8; ++t)
        #pragma unroll
        for (int c = 0; c < 4; ++c) a[t][c] = 0.0f;
    {
        const int jbase = w * 32;
        const float* ep = encT + (size_t)b * HD * SD + (size_t)jbase * SD + l * 4;
        #pragma unroll 4
        for (int jj = 0; jj < 32; ++jj) {
            float4 e = *(const float4*)(ep + (size_t)jj * SD);
            float vj = v[jbase + jj];
            float qv[8];
            #pragma unroll
            for (int t = 0; t < 8; ++t) qv[t] = qls[t * 512 + jbase + jj];
            float ev[4] = {e.x, e.y, e.z, e.w};
            #pragma unroll
            for (int t = 0; t < 8; ++t)
                #pragma unroll
                for (int c = 0; c < 4; ++c) {
                    float p = fmaf(ev[c], qv[t], 1.0f);
                    a[t][c] = fmaf(vj, RCP(p), a[t][c]);
                }
        }
    }
    if (w < 4) {
        #pragma unroll
        for (int t = 0; t < 8; ++t)
            *(float4*)&pls[(w * 8 + t) * 256 + l * 4] =
                make_float4(a[t][0], a[t][1], a[t][2], a[t][3]);
    }
    __syncthreads();
    if (w >= 4 && w < 8) {
        #pragma unroll
        for (int t = 0; t < 8; ++t) {
            float4 c4 = *(const float4*)&pls[((w - 4) * 8 + t) * 256 + l * 4];
            c4.x += a[t][0]; c4.y += a[t][1]; c4.z += a[t][2]; c4.w += a[t][3];
            *(float4*)&pls[((w - 4) * 8 + t) * 256 + l * 4] = c4;
        }
    }
    __syncthreads();
    if (w >= 8 && w < 12) {
        #pragma unroll
        for (int t = 0; t < 8; ++t) {
            float4 c4 = *(const float4*)&pls[((w - 8) * 8 + t) * 256 + l * 4];
            c4.x += a[t][0]; c4.y += a[t][1]; c4.z += a[t][2]; c4.w += a[t][3];
            *(float4*)&pls[((w - 8) * 8 + t) * 256 + l * 4] = c4;
        }
    }
    __syncthreads();
    if (w >= 12) {
        #pragma unroll
        for (int t = 0; t < 8; ++t) {
            float4 c4 = *(const float4*)&pls[((w - 12) * 8 + t) * 256 + l * 4];
            c4.x += a[t][0]; c4.y += a[t][1]; c4.z += a[t][2]; c4.w += a[t][3];
            *(float4*)&pls[((w - 12) * 8 + t) * 256 + l * 4] = c4;
        }
    }
    __syncthreads();

    if (w < 8) {
        const int t = w;
        float p[4] = {0, 0, 0, 0};
        #pragma unroll
        for (int g = 0; g < 4; ++g) {
            float4 pp = *(const float4*)&pls[(g * 8 + t) * 256 + l * 4];
            p[0] += pp.x; p[1] += pp.y; p[2] += pp.z; p[3] += pp.w;
        }
        const int len = lens[b];
        const int s0 = l * 4;
        float sc[4];
        #pragma unroll
        for (int c = 0; c < 4; ++c)
            sc[c] = (s0 + c < len) ? -2.0f * p[c] : -INFINITY;
        float mx = fmaxf(fmaxf(sc[0], sc[1]), fmaxf(sc[2], sc[3]));
        #pragma unroll
        for (int off = 32; off; off >>= 1) mx = fmaxf(mx, __shfl_xor(mx, off));
        float ex[4]; float sum = 0.0f;
        #pragma unroll
        for (int c = 0; c < 4; ++c) { ex[c] = __expf(sc[c] - mx); sum += ex[c]; }
        #pragma unroll
        for (int off = 32; off; off >>= 1) sum += __shfl_xor(sum, off);
        const float inv = RCP(sum);
        *(float4*)&wls[t * SD + s0] = make_float4(ex[0]*inv, ex[1]*inv, ex[2]*inv, ex[3]*inv);
    }
    __syncthreads();

    const int sg = tid >> 7;
    const int h4 = (tid & 127) * 4;
    float* avred = pls;
    float4 o[8];
    #pragma unroll
    for (int t = 0; t < 8; ++t) o[t] = make_float4(0.f, 0.f, 0.f, 0.f);
    {
        const float* eb = enc + (size_t)b * SD * HD + h4;
        #pragma unroll 2
        for (int ss = 0; ss < 32; ++ss) {
            const int s = sg * 32 + ss;
            float4 evv = *(const float4*)(eb + (size_t)s * HD);
            float wt[8];
            #pragma unroll
            for (int t = 0; t < 8; ++t) wt[t] = wls[t * SD + s];
            #pragma unroll
            for (int t = 0; t < 8; ++t) {
                o[t].x = fmaf(wt[t], evv.x, o[t].x);
                o[t].y = fmaf(wt[t], evv.y, o[t].y);
                o[t].z = fmaf(wt[t], evv.z, o[t].z);
                o[t].w = fmaf(wt[t], evv.w, o[t].w);
            }
        }
    }
    if (sg < 2) {
        #pragma unroll
        for (int t = 0; t < 8; ++t)
            *(float4*)&avred[(size_t)(sg * 8 + t) * 512 + h4] = o[t];
    }
    __syncthreads();
    if (sg >= 2 && sg < 4) {
        #pragma unroll
        for (int t = 0; t < 8; ++t) {
            float4 c4 = *(const float4*)&avred[(size_t)((sg - 2) * 8 + t) * 512 + h4];
            c4.x += o[t].x; c4.y += o[t].y; c4.z += o[t].z; c4.w += o[t].w;
            *(float4*)&avred[(size_t)((sg - 2) * 8 + t) * 512 + h4] = c4;
        }
    }
    __syncthreads();
    if (sg >= 4 && sg < 6) {
        #pragma unroll
        for (int t = 0; t < 8; ++t) {
            float4 c4 = *(const float4*)&avred[(size_t)((sg - 4) * 8 + t) * 512 + h4];
            c4.x += o[t].x; c4.y += o[t].y; c4.z += o[t].z; c4.w += o[t].w;
            *(float4*)&avred[(size_t)((sg - 4) * 8 + t) * 512 + h4] = c4;
        }
    }
    __syncthreads();
    if (sg >= 6) {
        #pragma unroll
        for (int t = 0; t < 8; ++t) {
            float4 c4 = *(const float4*)&avred[(size_t)((sg - 6) * 8 + t) * 512 + h4];
            c4.x += o[t].x; c4.y += o[t].y; c4.z += o[t].z; c4.w += o[t].w;
            *(float4*)&avred[(size_t)((sg - 6) * 8 + t) * 512 + h4] = c4;
        }
    }
    __syncthreads();

    {
        const int t  = tid >> 7;
        const int hh = (tid & 127) * 4;
        float4 x0 = *(const float4*)&avred[(size_t)(0 * 8 + t) * 512 + hh];
        float4 x1 = *(const float4*)&avred[(size_t)(1 * 8 + t) * 512 + hh];
        float4 r = make_float4(x0.x + x1.x, x0.y + x1.y, x0.z + x1.z, x0.w + x1.w);
        *(float4*)(out + ((size_t)b * TD + t0 + t) * HD + hh) = r;
    }
}

extern "C" void kernel_launch(void* const* d_in, const int* in_sizes, int n_in,
                              void* d_out, int out_size, void* d_ws, size_t ws_size,
                              hipStream_t stream) {
    const float* query = (const float*)d_in[0];
    const float* enc   = (const float*)d_in[1];
    const int*   lens  = (const int*)d_in[2];
    const float* W_h   = (const float*)d_in[3];
    const float* W_s   = (const float*)d_in[4];
    const float* v     = (const float*)d_in[5];
    float* out = (float*)d_out;

    char* ws = (char*)d_ws;
    float* encT = (float*)(ws);                       // 4 MB (B,H,S)  E_e
    float* qryf = (float*)(ws + ((size_t)4 << 20));   // 4 MB (B,T,H)  E_q
    float* part = (float*)(ws + ((size_t)8 << 20));   // 4 MB (B,T,2,S) score partials

    // Plain launches only — graph-capture-safe (R7 lesson).
    projK<<<dim3(512), dim3(1024), 0, stream>>>(enc, query, W_h, W_s, encT, qryf);

    // R8 lesson: pre-screen scoreK's register allocation (pure query, graph-safe).
    // Spill (localSizeBytes>0) or >64 VGPR (no 2 blocks/CU) -> proven attnK path.
    hipFuncAttributes fa{};
    bool split_ok = (ws_size >= ((size_t)12 << 20)) &&
                    (hipFuncGetAttributes(&fa, (const void*)scoreK) == hipSuccess) &&
                    (fa.localSizeBytes == 0) && (fa.numRegs <= 64);

    if (split_ok) {
        // j-halved score (2 blocks/CU) + proven softmax/AV tail.
        scoreK<<<dim3(512), dim3(1024), 0, stream>>>(encT, qryf, v, part);
        attn2K<<<dim3(512), dim3(512),  0, stream>>>(enc, part, lens, out);
    } else {
        // R7-proven fused attn (bench 119 us).
        attnK<<<dim3(256), dim3(1024), 0, stream>>>(enc, encT, qryf, v, lens, out);
    }
}